// Round 1
// baseline (189.956 us; speedup 1.0000x reference)
//
#include <hip/hip_runtime.h>
#include <cstdint>
#include <cstddef>

#define N_NODES 4096
#define NFEAT   512
#define NHID    64
#define NCLASS  40
#define NHEADS  4
#define ALPHA_S 0.2f

__device__ __forceinline__ float lrelu(float x) { return x > 0.f ? x : ALPHA_S * x; }

// broadcast a 64-bit value from srcLane across the wave
__device__ __forceinline__ unsigned long long bcast64(unsigned long long v, int srcLane) {
    int lo = (int)(unsigned)v;
    int hi = (int)(unsigned)(v >> 32);
    lo = __shfl(lo, srcLane);
    hi = __shfl(hi, srcLane);
    return ((unsigned long long)(unsigned)hi << 32) | (unsigned)(unsigned)lo;
}

// ---------------------------------------------------------------------------
// 1. adjacency bitmask from edge list (dedup via bits)
// ---------------------------------------------------------------------------
__global__ __launch_bounds__(256) void build_adj(const int* __restrict__ ei, int E,
                                                 unsigned long long* __restrict__ adj) {
    int t = blockIdx.x * 256 + threadIdx.x;
    if (t >= E) return;
    int r = ei[t];
    int c = ei[E + t];
    atomicOr(&adj[(size_t)r * 64 + (c >> 6)], 1ull << (c & 63));
}

// ---------------------------------------------------------------------------
// 2. Wh1[h] = x @ W1[h] + b1[h]   (4096x512 @ 512x64), f32, LDS-tiled
//    grid (64 row-tiles, 4 heads), 256 threads, 64x64 tile, 4x4 micro-tile
// ---------------------------------------------------------------------------
__global__ __launch_bounds__(256) void gemm1(const float* __restrict__ x,
                                             const float* __restrict__ W1,
                                             const float* __restrict__ b1,
                                             float* __restrict__ Wh) {
    const int h  = blockIdx.y;
    const int rt = blockIdx.x;
    __shared__ float xs[64][33];   // +1 pad: a-reads hit distinct banks
    __shared__ float ws[32][65];
    const int tid = threadIdx.x;
    const int ty = tid >> 4, tx = tid & 15;   // 16x16 threads, 4x4 each
    float acc[4][4] = {};
    const float* Wb = W1 + (size_t)h * NFEAT * NHID;

    for (int k0 = 0; k0 < NFEAT; k0 += 32) {
        // load x tile: 64 rows x 32 k  (512 float4, 2/thread)
        for (int f = tid; f < 512; f += 256) {
            int r = f >> 3, kq = f & 7;
            float4 v = *reinterpret_cast<const float4*>(
                &x[(size_t)(rt * 64 + r) * NFEAT + k0 + kq * 4]);
            xs[r][kq * 4 + 0] = v.x; xs[r][kq * 4 + 1] = v.y;
            xs[r][kq * 4 + 2] = v.z; xs[r][kq * 4 + 3] = v.w;
        }
        // load W tile: 32 k x 64 n (512 float4, 2/thread)
        for (int f = tid; f < 512; f += 256) {
            int k = f >> 4, nq = f & 15;
            float4 v = *reinterpret_cast<const float4*>(
                &Wb[(size_t)(k0 + k) * NHID + nq * 4]);
            ws[k][nq * 4 + 0] = v.x; ws[k][nq * 4 + 1] = v.y;
            ws[k][nq * 4 + 2] = v.z; ws[k][nq * 4 + 3] = v.w;
        }
        __syncthreads();
        #pragma unroll 8
        for (int kk = 0; kk < 32; ++kk) {
            float a[4], b[4];
            #pragma unroll
            for (int r = 0; r < 4; ++r) a[r] = xs[ty * 4 + r][kk];
            #pragma unroll
            for (int c = 0; c < 4; ++c) b[c] = ws[kk][tx * 4 + c];
            #pragma unroll
            for (int r = 0; r < 4; ++r)
                #pragma unroll
                for (int c = 0; c < 4; ++c) acc[r][c] += a[r] * b[c];
        }
        __syncthreads();
    }
    #pragma unroll
    for (int r = 0; r < 4; ++r) {
        int row = rt * 64 + ty * 4 + r;
        #pragma unroll
        for (int c = 0; c < 4; ++c) {
            int n = tx * 4 + c;
            Wh[((size_t)h * N_NODES + row) * NHID + n] = acc[r][c] + b1[h * NHID + n];
        }
    }
}

// ---------------------------------------------------------------------------
// 3. src/dst projections: one wave per (head,row); lane = feature
// ---------------------------------------------------------------------------
__global__ __launch_bounds__(256) void vec1(const float* __restrict__ Wh,
                                            const float* __restrict__ a1,
                                            float* __restrict__ src,
                                            float* __restrict__ dst) {
    int i = blockIdx.x;
    int h = threadIdx.x >> 6, lane = threadIdx.x & 63;
    float v = Wh[((size_t)h * N_NODES + i) * NHID + lane];
    float s = v * a1[h * 2 * NHID + lane];
    float d = v * a1[h * 2 * NHID + NHID + lane];
    #pragma unroll
    for (int o = 32; o; o >>= 1) { s += __shfl_xor(s, o); d += __shfl_xor(d, o); }
    if (lane == 0) {
        src[h * N_NODES + i] = s;
        dst[h * N_NODES + i] = d;
    }
}

// column mean of Wh per head (empty-row fallback)
__global__ __launch_bounds__(256) void colmean1(const float* __restrict__ Wh,
                                                float* __restrict__ cm) {
    int h = blockIdx.x;
    int col = threadIdx.x & 63, part = threadIdx.x >> 6;
    float s = 0.f;
    for (int r = part * 1024; r < (part + 1) * 1024; ++r)
        s += Wh[((size_t)h * N_NODES + r) * NHID + col];
    __shared__ float red[4][64];
    red[part][col] = s;
    __syncthreads();
    if (part == 0)
        cm[h * NHID + col] = (red[0][col] + red[1][col] + red[2][col] + red[3][col]) * (1.f / N_NODES);
}

// ---------------------------------------------------------------------------
// 4. sparse attention layer 1: block = row, wave = head, lane = feature
// ---------------------------------------------------------------------------
__global__ __launch_bounds__(256) void attn1(const unsigned long long* __restrict__ adj,
                                             const float* __restrict__ Wh,
                                             const float* __restrict__ src,
                                             const float* __restrict__ dst,
                                             const float* __restrict__ ab1,
                                             const float* __restrict__ cm,
                                             float* __restrict__ hout) {
    const int i = blockIdx.x;
    const int h = threadIdx.x >> 6, lane = threadIdx.x & 63;
    const unsigned long long word = adj[(size_t)i * 64 + lane];
    const float s_i = src[h * N_NODES + i];
    const float ab = ab1[h];
    const float* __restrict__ dsth = dst + h * N_NODES;

    // phase A: row max + degree (lane-parallel over bitmask words)
    float m = -1e30f;
    int deg = __popcll(word);
    {
        unsigned long long w2 = word;
        while (w2) {
            int b = __builtin_ctzll(w2); w2 &= w2 - 1;
            int j = lane * 64 + b;
            m = fmaxf(m, lrelu(s_i + dsth[j] + ab));
        }
    }
    #pragma unroll
    for (int o = 32; o; o >>= 1) {
        m = fmaxf(m, __shfl_xor(m, o));
        deg += __shfl_xor(deg, o);
    }

    const float* __restrict__ Whh = Wh + (size_t)h * N_NODES * NHID;
    float acc = 0.f, l = 0.f;
    if (deg == 0) {
        acc = cm[h * NHID + lane];
        l = 1.f;
    } else {
        // phase B: serial neighbor walk; all lanes share score, lane = feature
        for (int w = 0; w < 64; ++w) {
            unsigned long long wd = bcast64(word, w);
            while (wd) {
                int b = __builtin_ctzll(wd); wd &= wd - 1;
                int j = w * 64 + b;
                float s = lrelu(s_i + dsth[j] + ab);
                float e = __expf(s - m);
                l += e;
                acc += e * Whh[(size_t)j * NHID + lane];
            }
        }
    }
    float o = acc / l;
    o = o > 0.f ? o : __expf(o) - 1.f;   // elu
    hout[(size_t)i * (NHEADS * NHID) + h * NHID + lane] = o;
}

// ---------------------------------------------------------------------------
// 5. Who = h @ Wo + bo (4096x256 @ 256x40), fused src/dst. 8 rows/block.
// ---------------------------------------------------------------------------
__global__ __launch_bounds__(256) void gemm2(const float* __restrict__ hmat,
                                             const float* __restrict__ Wo,
                                             const float* __restrict__ bo,
                                             const float* __restrict__ ao,
                                             float* __restrict__ Who,
                                             float* __restrict__ srco,
                                             float* __restrict__ dsto) {
    const int r0 = blockIdx.x * 8;
    __shared__ float hs[8][256];
    __shared__ float who[8][NCLASS];
    const int tid = threadIdx.x;
    for (int f = tid; f < 512; f += 256) {
        int r = f >> 6, q = f & 63;
        float4 v = *reinterpret_cast<const float4*>(&hmat[(size_t)(r0 + r) * 256 + q * 4]);
        hs[r][q * 4 + 0] = v.x; hs[r][q * 4 + 1] = v.y;
        hs[r][q * 4 + 2] = v.z; hs[r][q * 4 + 3] = v.w;
    }
    __syncthreads();
    for (int o = tid; o < 8 * NCLASS; o += 256) {
        int r = o / NCLASS, n = o % NCLASS;
        float s = bo[n];
        for (int k = 0; k < 256; ++k) s += hs[r][k] * Wo[k * NCLASS + n];
        who[r][n] = s;
        Who[(size_t)(r0 + r) * NCLASS + n] = s;
    }
    __syncthreads();
    if (tid < 16) {
        int r = tid >> 1;
        bool isd = tid & 1;
        const float* av = ao + (isd ? NCLASS : 0);
        float s = 0.f;
        #pragma unroll
        for (int n = 0; n < NCLASS; ++n) s += who[r][n] * av[n];
        (isd ? dsto : srco)[r0 + r] = s;
    }
}

__global__ __launch_bounds__(256) void colmeano(const float* __restrict__ Who,
                                                float* __restrict__ cm) {
    int n = blockIdx.x;
    float s = 0.f;
    for (int r = threadIdx.x; r < N_NODES; r += 256) s += Who[(size_t)r * NCLASS + n];
    __shared__ float red[256];
    red[threadIdx.x] = s;
    __syncthreads();
    for (int st = 128; st; st >>= 1) {
        if (threadIdx.x < st) red[threadIdx.x] += red[threadIdx.x + st];
        __syncthreads();
    }
    if (threadIdx.x == 0) cm[n] = red[0] * (1.f / N_NODES);
}

// ---------------------------------------------------------------------------
// 6. output attention + elu + log_softmax. 4 rows/block, wave = row.
// ---------------------------------------------------------------------------
__global__ __launch_bounds__(256) void attn2(const unsigned long long* __restrict__ adj,
                                             const float* __restrict__ Who,
                                             const float* __restrict__ srco,
                                             const float* __restrict__ dsto,
                                             const float* __restrict__ abo_p,
                                             const float* __restrict__ cm,
                                             float* __restrict__ out) {
    const int i = blockIdx.x * 4 + (threadIdx.x >> 6);
    const int lane = threadIdx.x & 63;
    const float ab = abo_p[0];
    const unsigned long long word = adj[(size_t)i * 64 + lane];
    const float s_i = srco[i];

    float m = -1e30f;
    int deg = __popcll(word);
    {
        unsigned long long w2 = word;
        while (w2) {
            int b = __builtin_ctzll(w2); w2 &= w2 - 1;
            int j = lane * 64 + b;
            m = fmaxf(m, lrelu(s_i + dsto[j] + ab));
        }
    }
    #pragma unroll
    for (int o = 32; o; o >>= 1) {
        m = fmaxf(m, __shfl_xor(m, o));
        deg += __shfl_xor(deg, o);
    }

    float acc = 0.f, l = 0.f;
    if (deg == 0) {
        acc = (lane < NCLASS) ? cm[lane] : 0.f;
        l = 1.f;
    } else {
        for (int w = 0; w < 64; ++w) {
            unsigned long long wd = bcast64(word, w);
            while (wd) {
                int b = __builtin_ctzll(wd); wd &= wd - 1;
                int j = w * 64 + b;
                float s = lrelu(s_i + dsto[j] + ab);
                float e = __expf(s - m);
                l += e;
                if (lane < NCLASS) acc += e * Who[(size_t)j * NCLASS + lane];
            }
        }
    }
    float v = acc / l;
    v = v > 0.f ? v : __expf(v) - 1.f;   // elu

    // log_softmax over 40 classes within the wave
    float xv = (lane < NCLASS) ? v : -1e30f;
    float mx = xv;
    #pragma unroll
    for (int o = 32; o; o >>= 1) mx = fmaxf(mx, __shfl_xor(mx, o));
    float ex = (lane < NCLASS) ? __expf(v - mx) : 0.f;
    #pragma unroll
    for (int o = 32; o; o >>= 1) ex += __shfl_xor(ex, o);
    if (lane < NCLASS) out[(size_t)i * NCLASS + lane] = v - mx - logf(ex);
}

// ---------------------------------------------------------------------------
extern "C" void kernel_launch(void* const* d_in, const int* in_sizes, int n_in,
                              void* d_out, int out_size, void* d_ws, size_t ws_size,
                              hipStream_t stream) {
    const float* x   = (const float*)d_in[0];
    const int*   ei  = (const int*)d_in[1];
    const float* W1  = (const float*)d_in[2];
    const float* b1  = (const float*)d_in[3];
    const float* a1  = (const float*)d_in[4];
    const float* ab1 = (const float*)d_in[5];
    const float* Wo  = (const float*)d_in[6];
    const float* bo  = (const float*)d_in[7];
    const float* ao  = (const float*)d_in[8];
    const float* abo = (const float*)d_in[9];
    float* out = (float*)d_out;
    const int E = in_sizes[1] / 2;

    size_t off = 0;
    char* base = (char*)d_ws;
    auto alloc = [&](size_t bytes) {
        void* p = base + off;
        off += (bytes + 255) & ~(size_t)255;
        return p;
    };
    unsigned long long* adj = (unsigned long long*)alloc((size_t)N_NODES * 64 * 8);
    float* Wh1  = (float*)alloc((size_t)NHEADS * N_NODES * NHID * 4);
    float* src1 = (float*)alloc((size_t)NHEADS * N_NODES * 4);
    float* dst1 = (float*)alloc((size_t)NHEADS * N_NODES * 4);
    float* cm1  = (float*)alloc((size_t)NHEADS * NHID * 4);
    float* hmat = (float*)alloc((size_t)N_NODES * NHEADS * NHID * 4);
    float* Who  = (float*)alloc((size_t)N_NODES * NCLASS * 4);
    float* srco = (float*)alloc((size_t)N_NODES * 4);
    float* dsto = (float*)alloc((size_t)N_NODES * 4);
    float* cmo  = (float*)alloc((size_t)NCLASS * 4);

    hipMemsetAsync(adj, 0, (size_t)N_NODES * 64 * 8, stream);
    build_adj<<<(E + 255) / 256, 256, 0, stream>>>(ei, E, adj);
    gemm1<<<dim3(N_NODES / 64, NHEADS), 256, 0, stream>>>(x, W1, b1, Wh1);
    vec1<<<N_NODES, 256, 0, stream>>>(Wh1, a1, src1, dst1);
    colmean1<<<NHEADS, 256, 0, stream>>>(Wh1, cm1);
    attn1<<<N_NODES, 256, 0, stream>>>(adj, Wh1, src1, dst1, ab1, cm1, hmat);
    gemm2<<<N_NODES / 8, 256, 0, stream>>>(hmat, Wo, bo, ao, Who, srco, dsto);
    colmeano<<<NCLASS, 256, 0, stream>>>(Who, cmo);
    attn2<<<N_NODES / 4, 256, 0, stream>>>(adj, Who, srco, dsto, abo, cmo, out);
}

// Round 2
// 98.860 us; speedup vs baseline: 1.9215x; 1.9215x over previous
//
#include <hip/hip_runtime.h>
#include <cstdint>
#include <cstddef>

#define N_NODES 4096
#define NFEAT   512
#define NHID    64
#define NCLASS  40
#define NHEADS  4
#define ALPHA_S 0.2f
#define MAXD    96

typedef __bf16 bf16x8 __attribute__((ext_vector_type(8)));
typedef float  f32x4  __attribute__((ext_vector_type(4)));

__device__ __forceinline__ float lrelu(float x) { return x > 0.f ? x : ALPHA_S * x; }

__device__ __forceinline__ unsigned short f2bf(float f) {
    unsigned u = __float_as_uint(f);
    u += 0x7fffu + ((u >> 16) & 1u);          // round-to-nearest-even
    return (unsigned short)(u >> 16);
}

__device__ __forceinline__ float wredmax(float m) {
    #pragma unroll
    for (int o = 32; o; o >>= 1) m = fmaxf(m, __shfl_xor(m, o));
    return m;
}
__device__ __forceinline__ float wredsum(float s) {
    #pragma unroll
    for (int o = 32; o; o >>= 1) s += __shfl_xor(s, o);
    return s;
}

// ---------------------------------------------------------------------------
// adjacency bitmask from edge list (dedup via bits)
// ---------------------------------------------------------------------------
__global__ __launch_bounds__(256) void build_adj(const int* __restrict__ ei, int E,
                                                 unsigned long long* __restrict__ adj) {
    int t = blockIdx.x * 256 + threadIdx.x;
    if (t >= E) return;
    int r = ei[t];
    int c = ei[E + t];
    atomicOr(&adj[(size_t)r * 64 + (c >> 6)], 1ull << (c & 63));
}

// ---------------------------------------------------------------------------
// bitmask -> compact neighbor lists (u16), one wave per row
// ---------------------------------------------------------------------------
__global__ __launch_bounds__(256) void compact(const unsigned long long* __restrict__ adj,
                                               int* __restrict__ deg,
                                               unsigned short* __restrict__ nbr) {
    const int i = blockIdx.x * 4 + (threadIdx.x >> 6);
    const int lane = threadIdx.x & 63;
    unsigned long long w = adj[(size_t)i * 64 + lane];
    int c = __popcll(w);
    int pre = c;
    #pragma unroll
    for (int o = 1; o < 64; o <<= 1) {
        int v = __shfl_up(pre, o);
        if (lane >= o) pre += v;
    }
    int total = __shfl(pre, 63);
    int base = pre - c;
    if (lane == 0) deg[i] = total < MAXD ? total : MAXD;
    while (w) {
        int b = __builtin_ctzll(w); w &= w - 1;
        if (base < MAXD) nbr[(size_t)i * MAXD + base] = (unsigned short)(lane * 64 + b);
        ++base;
    }
}

// ---------------------------------------------------------------------------
// fused casts: x->bf16 [4096][512]; W1->Bt bf16 [256][512] (n=h*64+c, transposed);
//              Wo->Wot bf16 [64][256] (zero-padded cols 40..63)
// ---------------------------------------------------------------------------
__global__ __launch_bounds__(256) void castall(const float* __restrict__ x,
                                               const float* __restrict__ W1,
                                               const float* __restrict__ Wo,
                                               unsigned short* __restrict__ xb,
                                               unsigned short* __restrict__ Bt,
                                               unsigned short* __restrict__ Wot) {
    const int bid = blockIdx.x, t = threadIdx.x;
    if (bid < 1024) {                       // x cast: 8 elems/thread
        size_t idx = (size_t)bid * 2048 + t * 8;
        float4 v0 = *reinterpret_cast<const float4*>(x + idx);
        float4 v1 = *reinterpret_cast<const float4*>(x + idx + 4);
        uint4 o;
        o.x = (unsigned)f2bf(v0.x) | ((unsigned)f2bf(v0.y) << 16);
        o.y = (unsigned)f2bf(v0.z) | ((unsigned)f2bf(v0.w) << 16);
        o.z = (unsigned)f2bf(v1.x) | ((unsigned)f2bf(v1.y) << 16);
        o.w = (unsigned)f2bf(v1.z) | ((unsigned)f2bf(v1.w) << 16);
        *reinterpret_cast<uint4*>(xb + idx) = o;
    } else if (bid < 1280) {                // Bt row n
        int n = bid - 1024;
        int h = n >> 6, c = n & 63;
        for (int k = t; k < NFEAT; k += 256)
            Bt[(size_t)n * NFEAT + k] = f2bf(W1[(size_t)h * NFEAT * NHID + (size_t)k * NHID + c]);
    } else {                                // Wot row n
        int n = bid - 1280;
        int k = t;
        unsigned short v = 0;
        if (n < NCLASS) v = f2bf(Wo[(size_t)k * NCLASS + n]);
        Wot[(size_t)n * 256 + k] = v;
    }
}

// ---------------------------------------------------------------------------
// bf16 MFMA GEMM: C[(nt*4096+row)*ldc+col] = A[4096xK] @ B[nt-block, 64xK]^T + bias
// tile 64x64, BK=64, 4 waves (2x2), XOR-swizzled LDS, 16x16x32 MFMA
// ---------------------------------------------------------------------------
__global__ __launch_bounds__(256) void gemm_mfma(const unsigned short* __restrict__ A,
                                                 const unsigned short* __restrict__ B,
                                                 const float* __restrict__ bias_,
                                                 float* __restrict__ C,
                                                 int K, int ldc, int ncols) {
    const int rt = blockIdx.x;
    const int nt = blockIdx.y;
    __shared__ unsigned short As[64 * 64];
    __shared__ unsigned short Bs[64 * 64];
    const int tid = threadIdx.x;
    const int wid = tid >> 6, l = tid & 63;
    const int wr = wid >> 1, wc = wid & 1;

    f32x4 acc[2][2] = {};

    // precompute swizzled LDS read offsets (elements)
    int aoff[2][2], boff[2][2];
    #pragma unroll
    for (int f = 0; f < 2; ++f) {
        int r = wr * 32 + f * 16 + (l & 15);
        int c = wc * 32 + f * 16 + (l & 15);
        #pragma unroll
        for (int s = 0; s < 2; ++s) {
            int gk = (s << 2) + (l >> 4);
            aoff[f][s] = r * 64 + ((gk ^ (r & 7)) << 3);
            boff[f][s] = c * 64 + ((gk ^ (c & 7)) << 3);
        }
    }
    const unsigned short* Ab = A + (size_t)(rt * 64) * K;
    const unsigned short* Bb = B + (size_t)(nt * 64) * K;

    for (int k0 = 0; k0 < K; k0 += 64) {
        #pragma unroll
        for (int g = tid; g < 512; g += 256) {
            int row = g >> 3, gc = g & 7;
            uint4 va = *reinterpret_cast<const uint4*>(Ab + (size_t)row * K + k0 + (gc << 3));
            *reinterpret_cast<uint4*>(As + row * 64 + (((gc ^ (row & 7)) << 3))) = va;
            uint4 vb = *reinterpret_cast<const uint4*>(Bb + (size_t)row * K + k0 + (gc << 3));
            *reinterpret_cast<uint4*>(Bs + row * 64 + (((gc ^ (row & 7)) << 3))) = vb;
        }
        __syncthreads();
        #pragma unroll
        for (int s = 0; s < 2; ++s) {
            bf16x8 av[2], bv[2];
            #pragma unroll
            for (int f = 0; f < 2; ++f) {
                av[f] = *reinterpret_cast<const bf16x8*>(As + aoff[f][s]);
                bv[f] = *reinterpret_cast<const bf16x8*>(Bs + boff[f][s]);
            }
            #pragma unroll
            for (int fa = 0; fa < 2; ++fa)
                #pragma unroll
                for (int fb = 0; fb < 2; ++fb)
                    acc[fa][fb] = __builtin_amdgcn_mfma_f32_16x16x32_bf16(
                        av[fa], bv[fb], acc[fa][fb], 0, 0, 0);
        }
        __syncthreads();
    }
    // epilogue: C/D layout col=lane&15, row=(lane>>4)*4+reg  [m89]
    #pragma unroll
    for (int fa = 0; fa < 2; ++fa) {
        #pragma unroll
        for (int fb = 0; fb < 2; ++fb) {
            int col_l = wc * 32 + fb * 16 + (l & 15);
            if (col_l < ncols) {
                float bias = bias_[nt * 64 + col_l];
                #pragma unroll
                for (int j = 0; j < 4; ++j) {
                    int row_l = wr * 32 + fa * 16 + ((l >> 4) << 2) + j;
                    C[((size_t)nt * N_NODES + rt * 64 + row_l) * ldc + col_l] = acc[fa][fb][j] + bias;
                }
            }
        }
    }
}

// ---------------------------------------------------------------------------
// vec1 + colmean1 fused: grid 4096 (src/dst proj) + 4 (per-head colmean)
// ---------------------------------------------------------------------------
__global__ __launch_bounds__(256) void vecmean1(const float* __restrict__ Wh,
                                                const float* __restrict__ a1,
                                                float* __restrict__ src,
                                                float* __restrict__ dst,
                                                float* __restrict__ cm) {
    const int bid = blockIdx.x;
    if (bid < N_NODES) {
        int i = bid;
        int h = threadIdx.x >> 6, lane = threadIdx.x & 63;
        float v = Wh[((size_t)h * N_NODES + i) * NHID + lane];
        float s = v * a1[h * 2 * NHID + lane];
        float d = v * a1[h * 2 * NHID + NHID + lane];
        s = wredsum(s); d = wredsum(d);
        if (lane == 0) {
            src[h * N_NODES + i] = s;
            dst[h * N_NODES + i] = d;
        }
    } else {
        int h = bid - N_NODES;
        int col = threadIdx.x & 63, part = threadIdx.x >> 6;
        float s = 0.f;
        for (int r = part * 1024; r < (part + 1) * 1024; ++r)
            s += Wh[((size_t)h * N_NODES + r) * NHID + col];
        __shared__ float red[4][64];
        red[part][col] = s;
        __syncthreads();
        if (part == 0)
            cm[h * NHID + col] = (red[0][col] + red[1][col] + red[2][col] + red[3][col]) * (1.f / N_NODES);
    }
}

// ---------------------------------------------------------------------------
// sparse attention layer 1 (compact lists): block=row, wave=head, lane=feature
// writes h (elu'd, concat) directly as bf16
// ---------------------------------------------------------------------------
__global__ __launch_bounds__(256) void attn1(const float* __restrict__ Wh,
                                             const float* __restrict__ src,
                                             const float* __restrict__ dst,
                                             const float* __restrict__ ab1,
                                             const float* __restrict__ cm,
                                             const int* __restrict__ deg,
                                             const unsigned short* __restrict__ nbr,
                                             unsigned short* __restrict__ hb) {
    const int i = blockIdx.x;
    const int h = threadIdx.x >> 6, lane = threadIdx.x & 63;
    __shared__ unsigned short nb[MAXD];
    __shared__ float ev[NHEADS][MAXD];
    const int d = deg[i];
    for (int q = threadIdx.x; q < d; q += 256) nb[q] = nbr[(size_t)i * MAXD + q];
    __syncthreads();

    const float s_i = src[h * N_NODES + i];
    const float ab = ab1[h];
    const float* __restrict__ dsth = dst + h * N_NODES;

    float m = -1e30f;
    for (int q = lane; q < d; q += 64) m = fmaxf(m, lrelu(s_i + dsth[nb[q]] + ab));
    m = wredmax(m);

    float lp = 0.f;
    for (int q = lane; q < d; q += 64) {
        float e = __expf(lrelu(s_i + dsth[nb[q]] + ab) - m);
        ev[h][q] = e;
        lp += e;
    }
    float l = wredsum(lp);
    __syncthreads();

    float acc = 0.f;
    const float* __restrict__ Whh = Wh + (size_t)h * N_NODES * NHID;
    if (d == 0) {
        acc = cm[h * NHID + lane];
    } else {
        #pragma unroll 4
        for (int q = 0; q < d; ++q) {
            float e = ev[h][q];
            int j = nb[q];
            acc += e * Whh[(size_t)j * NHID + lane];
        }
        acc *= (1.f / l);
    }
    float o = acc > 0.f ? acc : __expf(acc) - 1.f;   // elu
    hb[(size_t)i * (NHEADS * NHID) + h * NHID + lane] = f2bf(o);
}

// ---------------------------------------------------------------------------
// vec2 + colmeano fused: grid 1024 (4 rows/block src/dst) + 40 (colmean)
// ---------------------------------------------------------------------------
__global__ __launch_bounds__(256) void vecmean2(const float* __restrict__ Who,
                                                const float* __restrict__ ao,
                                                float* __restrict__ srco,
                                                float* __restrict__ dsto,
                                                float* __restrict__ cm) {
    const int bid = blockIdx.x;
    if (bid < 1024) {
        int i = bid * 4 + (threadIdx.x >> 6);
        int lane = threadIdx.x & 63;
        float v = (lane < NCLASS) ? Who[(size_t)i * NCLASS + lane] : 0.f;
        float s = (lane < NCLASS) ? v * ao[lane] : 0.f;
        float d = (lane < NCLASS) ? v * ao[NCLASS + lane] : 0.f;
        s = wredsum(s); d = wredsum(d);
        if (lane == 0) { srco[i] = s; dsto[i] = d; }
    } else {
        int n = bid - 1024;
        float s = 0.f;
        for (int r = threadIdx.x; r < N_NODES; r += 256) s += Who[(size_t)r * NCLASS + n];
        __shared__ float red[256];
        red[threadIdx.x] = s;
        __syncthreads();
        for (int st = 128; st; st >>= 1) {
            if (threadIdx.x < st) red[threadIdx.x] += red[threadIdx.x + st];
            __syncthreads();
        }
        if (threadIdx.x == 0) cm[n] = red[0] * (1.f / N_NODES);
    }
}

// ---------------------------------------------------------------------------
// output attention + elu + log_softmax: 4 rows/block, wave=row
// ---------------------------------------------------------------------------
__global__ __launch_bounds__(256) void attn2(const float* __restrict__ Who,
                                             const float* __restrict__ srco,
                                             const float* __restrict__ dsto,
                                             const float* __restrict__ abo_p,
                                             const float* __restrict__ cm,
                                             const int* __restrict__ deg,
                                             const unsigned short* __restrict__ nbr,
                                             float* __restrict__ out) {
    const int wid = threadIdx.x >> 6;
    const int i = blockIdx.x * 4 + wid;
    const int lane = threadIdx.x & 63;
    __shared__ unsigned short nb[4][MAXD];
    __shared__ float ev[4][MAXD];
    const float ab = abo_p[0];
    const int d = deg[i];
    for (int q = lane; q < d; q += 64) nb[wid][q] = nbr[(size_t)i * MAXD + q];
    const float s_i = srco[i];

    float m = -1e30f;
    for (int q = lane; q < d; q += 64) m = fmaxf(m, lrelu(s_i + dsto[nb[wid][q]] + ab));
    m = wredmax(m);

    float lp = 0.f;
    for (int q = lane; q < d; q += 64) {
        float e = __expf(lrelu(s_i + dsto[nb[wid][q]] + ab) - m);
        ev[wid][q] = e;
        lp += e;
    }
    float l = wredsum(lp);
    __syncthreads();

    float acc = 0.f;
    if (d == 0) {
        acc = (lane < NCLASS) ? cm[lane] : 0.f;
    } else {
        #pragma unroll 4
        for (int q = 0; q < d; ++q) {
            float e = ev[wid][q];
            int j = nb[wid][q];
            if (lane < NCLASS) acc += e * Who[(size_t)j * NCLASS + lane];
        }
        acc *= (1.f / l);
    }
    float v = acc > 0.f ? acc : __expf(acc) - 1.f;   // elu

    float xv = (lane < NCLASS) ? v : -1e30f;
    float mx = wredmax(xv);
    float ex = (lane < NCLASS) ? __expf(v - mx) : 0.f;
    ex = wredsum(ex);
    if (lane < NCLASS) out[(size_t)i * NCLASS + lane] = v - mx - logf(ex);
}

// ---------------------------------------------------------------------------
extern "C" void kernel_launch(void* const* d_in, const int* in_sizes, int n_in,
                              void* d_out, int out_size, void* d_ws, size_t ws_size,
                              hipStream_t stream) {
    const float* x   = (const float*)d_in[0];
    const int*   ei  = (const int*)d_in[1];
    const float* W1  = (const float*)d_in[2];
    const float* b1  = (const float*)d_in[3];
    const float* a1  = (const float*)d_in[4];
    const float* ab1 = (const float*)d_in[5];
    const float* Wo  = (const float*)d_in[6];
    const float* bo  = (const float*)d_in[7];
    const float* ao  = (const float*)d_in[8];
    const float* abo = (const float*)d_in[9];
    float* out = (float*)d_out;
    const int E = in_sizes[1] / 2;

    char* base = (char*)d_ws;
    const size_t MB = 1024 * 1024;
    // region 0: adj (2MB) -> reused as hb (bf16 4096x256 = 2MB) after compact
    unsigned long long* adj = (unsigned long long*)(base);
    unsigned short*     hb  = (unsigned short*)(base);
    // region 1: xb (bf16 4096x512 = 4MB) -> reused for Who/srco/dsto/cmo after gemm1
    unsigned short* xb   = (unsigned short*)(base + 2 * MB);
    float*          Who  = (float*)(base + 2 * MB);                 // 640KB
    float*          srco = (float*)(base + 3 * MB);                 // 16KB
    float*          dsto = (float*)(base + 3 * MB + 16384);         // 16KB
    float*          cmo  = (float*)(base + 3 * MB + 32768);         // small
    // region 2: Wh1 f32 [4][4096][64] = 4MB
    float* Wh1 = (float*)(base + 6 * MB);
    // region 3: persistent small buffers
    unsigned short* Bt   = (unsigned short*)(base + 10 * MB);            // 256KB
    unsigned short* Wot  = (unsigned short*)(base + 10 * MB + 262144);   // 32KB
    float*          src1 = (float*)(base + 10 * MB + 262144 + 32768);    // 64KB
    float*          dst1 = (float*)(base + 10 * MB + 262144 + 32768 + 65536);
    float*          cm1  = (float*)(base + 10 * MB + 262144 + 32768 + 131072);  // 1KB
    int*            deg  = (int*)(base + 10 * MB + 262144 + 32768 + 131072 + 4096); // 16KB
    unsigned short* nbr  = (unsigned short*)(base + 10 * MB + 262144 + 32768 + 131072 + 4096 + 16384); // 768KB

    hipMemsetAsync(adj, 0, (size_t)N_NODES * 64 * 8, stream);
    build_adj<<<(E + 255) / 256, 256, 0, stream>>>(ei, E, adj);
    compact<<<N_NODES / 4, 256, 0, stream>>>(adj, deg, nbr);
    castall<<<1344, 256, 0, stream>>>(x, W1, Wo, xb, Bt, Wot);
    gemm_mfma<<<dim3(64, NHEADS), 256, 0, stream>>>(xb, Bt, b1, Wh1, NFEAT, NHID, NHID);
    vecmean1<<<N_NODES + NHEADS, 256, 0, stream>>>(Wh1, a1, src1, dst1, cm1);
    attn1<<<N_NODES, 256, 0, stream>>>(Wh1, src1, dst1, ab1, cm1, deg, nbr, hb);
    gemm_mfma<<<dim3(64, 1), 256, 0, stream>>>(hb, Wot, bo, Who, NHEADS * NHID, NCLASS, NCLASS);
    vecmean2<<<1024 + NCLASS, 256, 0, stream>>>(Who, ao, srco, dsto, cmo);
    attn2<<<N_NODES / 4, 256, 0, stream>>>(Who, srco, dsto, abo, cmo, deg, nbr, out);
}

// Round 3
// 94.296 us; speedup vs baseline: 2.0145x; 1.0484x over previous
//
#include <hip/hip_runtime.h>
#include <cstdint>
#include <cstddef>

#define N_NODES 4096
#define NFEAT   512
#define NHID    64
#define NCLASS  40
#define NHEADS  4
#define ALPHA_S 0.2f
#define MAXD    96

typedef __bf16 bf16x8 __attribute__((ext_vector_type(8)));
typedef float  f32x4  __attribute__((ext_vector_type(4)));

__device__ __forceinline__ float lrelu(float x) { return x > 0.f ? x : ALPHA_S * x; }

__device__ __forceinline__ unsigned short f2bf(float f) {
    unsigned u = __float_as_uint(f);
    u += 0x7fffu + ((u >> 16) & 1u);          // round-to-nearest-even
    return (unsigned short)(u >> 16);
}

__device__ __forceinline__ float wredmax(float m) {
    #pragma unroll
    for (int o = 32; o; o >>= 1) m = fmaxf(m, __shfl_xor(m, o));
    return m;
}
__device__ __forceinline__ float wredsum(float s) {
    #pragma unroll
    for (int o = 32; o; o >>= 1) s += __shfl_xor(s, o);
    return s;
}

// ---------------------------------------------------------------------------
// adjacency bitmask from edge list (dedup via bits)
// ---------------------------------------------------------------------------
__global__ __launch_bounds__(256) void build_adj(const int* __restrict__ ei, int E,
                                                 unsigned long long* __restrict__ adj) {
    int t = blockIdx.x * 256 + threadIdx.x;
    if (t >= E) return;
    int r = ei[t];
    int c = ei[E + t];
    atomicOr(&adj[(size_t)r * 64 + (c >> 6)], 1ull << (c & 63));
}

// ---------------------------------------------------------------------------
// bitmask -> compact neighbor lists (u16), one wave per row
// ---------------------------------------------------------------------------
__global__ __launch_bounds__(256) void compact(const unsigned long long* __restrict__ adj,
                                               int* __restrict__ deg,
                                               unsigned short* __restrict__ nbr) {
    const int i = blockIdx.x * 4 + (threadIdx.x >> 6);
    const int lane = threadIdx.x & 63;
    unsigned long long w = adj[(size_t)i * 64 + lane];
    int c = __popcll(w);
    int pre = c;
    #pragma unroll
    for (int o = 1; o < 64; o <<= 1) {
        int v = __shfl_up(pre, o);
        if (lane >= o) pre += v;
    }
    int total = __shfl(pre, 63);
    int base = pre - c;
    if (lane == 0) deg[i] = total < MAXD ? total : MAXD;
    while (w) {
        int b = __builtin_ctzll(w); w &= w - 1;
        if (base < MAXD) nbr[(size_t)i * MAXD + base] = (unsigned short)(lane * 64 + b);
        ++base;
    }
}

// ---------------------------------------------------------------------------
// fused: zero adj bitmask; casts x->bf16 [4096][512];
//        W1->Bt bf16 [256][512] (n=h*64+c, transposed);
//        Wo->Wot bf16 [64][256] (zero-padded cols 40..63)
// grid: 1024 (x) + 256 (Bt) + 64 (Wot) + 128 (zero adj) = 1472
// ---------------------------------------------------------------------------
__global__ __launch_bounds__(256) void castall(const float* __restrict__ x,
                                               const float* __restrict__ W1,
                                               const float* __restrict__ Wo,
                                               unsigned short* __restrict__ xb,
                                               unsigned short* __restrict__ Bt,
                                               unsigned short* __restrict__ Wot,
                                               uint4* __restrict__ adj4) {
    const int bid = blockIdx.x, t = threadIdx.x;
    if (bid < 1024) {                       // x cast: 8 elems/thread
        size_t idx = (size_t)bid * 2048 + t * 8;
        float4 v0 = *reinterpret_cast<const float4*>(x + idx);
        float4 v1 = *reinterpret_cast<const float4*>(x + idx + 4);
        uint4 o;
        o.x = (unsigned)f2bf(v0.x) | ((unsigned)f2bf(v0.y) << 16);
        o.y = (unsigned)f2bf(v0.z) | ((unsigned)f2bf(v0.w) << 16);
        o.z = (unsigned)f2bf(v1.x) | ((unsigned)f2bf(v1.y) << 16);
        o.w = (unsigned)f2bf(v1.z) | ((unsigned)f2bf(v1.w) << 16);
        *reinterpret_cast<uint4*>(xb + idx) = o;
    } else if (bid < 1280) {                // Bt row n
        int n = bid - 1024;
        int h = n >> 6, c = n & 63;
        for (int k = t; k < NFEAT; k += 256)
            Bt[(size_t)n * NFEAT + k] = f2bf(W1[(size_t)h * NFEAT * NHID + (size_t)k * NHID + c]);
    } else if (bid < 1344) {                // Wot row n
        int n = bid - 1280;
        int k = t;
        unsigned short v = 0;
        if (n < NCLASS) v = f2bf(Wo[(size_t)k * NCLASS + n]);
        Wot[(size_t)n * 256 + k] = v;
    } else {                                // zero adj: 128 blocks x 1024 uint4
        uint4 z = {0, 0, 0, 0};
        uint4* p = adj4 + (size_t)(bid - 1344) * 1024 + t;
        p[0] = z; p[256] = z; p[512] = z; p[768] = z;
    }
}

// ---------------------------------------------------------------------------
// bf16 MFMA GEMM: C[(nt*4096+row)*ldc+col] = A[4096xK] @ B[nt-block, 64xK]^T + bias
// tile 64x64, BK=64, 4 waves (2x2), XOR-swizzled LDS, 16x16x32 MFMA
// ---------------------------------------------------------------------------
__global__ __launch_bounds__(256) void gemm_mfma(const unsigned short* __restrict__ A,
                                                 const unsigned short* __restrict__ B,
                                                 const float* __restrict__ bias_,
                                                 float* __restrict__ C,
                                                 int K, int ldc, int ncols) {
    const int rt = blockIdx.x;
    const int nt = blockIdx.y;
    __shared__ unsigned short As[64 * 64];
    __shared__ unsigned short Bs[64 * 64];
    const int tid = threadIdx.x;
    const int wid = tid >> 6, l = tid & 63;
    const int wr = wid >> 1, wc = wid & 1;

    f32x4 acc[2][2] = {};

    // precompute swizzled LDS read offsets (elements)
    int aoff[2][2], boff[2][2];
    #pragma unroll
    for (int f = 0; f < 2; ++f) {
        int r = wr * 32 + f * 16 + (l & 15);
        int c = wc * 32 + f * 16 + (l & 15);
        #pragma unroll
        for (int s = 0; s < 2; ++s) {
            int gk = (s << 2) + (l >> 4);
            aoff[f][s] = r * 64 + ((gk ^ (r & 7)) << 3);
            boff[f][s] = c * 64 + ((gk ^ (c & 7)) << 3);
        }
    }
    const unsigned short* Ab = A + (size_t)(rt * 64) * K;
    const unsigned short* Bb = B + (size_t)(nt * 64) * K;

    for (int k0 = 0; k0 < K; k0 += 64) {
        #pragma unroll
        for (int g = tid; g < 512; g += 256) {
            int row = g >> 3, gc = g & 7;
            uint4 va = *reinterpret_cast<const uint4*>(Ab + (size_t)row * K + k0 + (gc << 3));
            *reinterpret_cast<uint4*>(As + row * 64 + (((gc ^ (row & 7)) << 3))) = va;
            uint4 vb = *reinterpret_cast<const uint4*>(Bb + (size_t)row * K + k0 + (gc << 3));
            *reinterpret_cast<uint4*>(Bs + row * 64 + (((gc ^ (row & 7)) << 3))) = vb;
        }
        __syncthreads();
        #pragma unroll
        for (int s = 0; s < 2; ++s) {
            bf16x8 av[2], bv[2];
            #pragma unroll
            for (int f = 0; f < 2; ++f) {
                av[f] = *reinterpret_cast<const bf16x8*>(As + aoff[f][s]);
                bv[f] = *reinterpret_cast<const bf16x8*>(Bs + boff[f][s]);
            }
            #pragma unroll
            for (int fa = 0; fa < 2; ++fa)
                #pragma unroll
                for (int fb = 0; fb < 2; ++fb)
                    acc[fa][fb] = __builtin_amdgcn_mfma_f32_16x16x32_bf16(
                        av[fa], bv[fb], acc[fa][fb], 0, 0, 0);
        }
        __syncthreads();
    }
    // epilogue: C/D layout col=lane&15, row=(lane>>4)*4+reg  [m89]
    #pragma unroll
    for (int fa = 0; fa < 2; ++fa) {
        #pragma unroll
        for (int fb = 0; fb < 2; ++fb) {
            int col_l = wc * 32 + fb * 16 + (l & 15);
            if (col_l < ncols) {
                float bias = bias_[nt * 64 + col_l];
                #pragma unroll
                for (int j = 0; j < 4; ++j) {
                    int row_l = wr * 32 + fa * 16 + ((l >> 4) << 2) + j;
                    C[((size_t)nt * N_NODES + rt * 64 + row_l) * ldc + col_l] = acc[fa][fb][j] + bias;
                }
            }
        }
    }
}

// ---------------------------------------------------------------------------
// vec1 + colmean1 fused: grid 4096 (src/dst proj) + 4 (per-head colmean)
// ---------------------------------------------------------------------------
__global__ __launch_bounds__(256) void vecmean1(const float* __restrict__ Wh,
                                                const float* __restrict__ a1,
                                                float* __restrict__ src,
                                                float* __restrict__ dst,
                                                float* __restrict__ cm) {
    const int bid = blockIdx.x;
    if (bid < N_NODES) {
        int i = bid;
        int h = threadIdx.x >> 6, lane = threadIdx.x & 63;
        float v = Wh[((size_t)h * N_NODES + i) * NHID + lane];
        float s = v * a1[h * 2 * NHID + lane];
        float d = v * a1[h * 2 * NHID + NHID + lane];
        s = wredsum(s); d = wredsum(d);
        if (lane == 0) {
            src[h * N_NODES + i] = s;
            dst[h * N_NODES + i] = d;
        }
    } else {
        int h = bid - N_NODES;
        int col = threadIdx.x & 63, part = threadIdx.x >> 6;
        float s = 0.f;
        for (int r = part * 1024; r < (part + 1) * 1024; ++r)
            s += Wh[((size_t)h * N_NODES + r) * NHID + col];
        __shared__ float red[4][64];
        red[part][col] = s;
        __syncthreads();
        if (part == 0)
            cm[h * NHID + col] = (red[0][col] + red[1][col] + red[2][col] + red[3][col]) * (1.f / N_NODES);
    }
}

// ---------------------------------------------------------------------------
// sparse attention layer 1 (compact lists): block=row, wave=head, lane=feature
// writes h (elu'd, concat) directly as bf16
// ---------------------------------------------------------------------------
__global__ __launch_bounds__(256) void attn1(const float* __restrict__ Wh,
                                             const float* __restrict__ src,
                                             const float* __restrict__ dst,
                                             const float* __restrict__ ab1,
                                             const float* __restrict__ cm,
                                             const int* __restrict__ deg,
                                             const unsigned short* __restrict__ nbr,
                                             unsigned short* __restrict__ hb) {
    const int i = blockIdx.x;
    const int h = threadIdx.x >> 6, lane = threadIdx.x & 63;
    __shared__ unsigned short nb[MAXD];
    __shared__ float ev[NHEADS][MAXD];
    const int d = deg[i];
    for (int q = threadIdx.x; q < d; q += 256) nb[q] = nbr[(size_t)i * MAXD + q];
    __syncthreads();

    const float s_i = src[h * N_NODES + i];
    const float ab = ab1[h];
    const float* __restrict__ dsth = dst + h * N_NODES;

    float m = -1e30f;
    for (int q = lane; q < d; q += 64) m = fmaxf(m, lrelu(s_i + dsth[nb[q]] + ab));
    m = wredmax(m);

    float lp = 0.f;
    for (int q = lane; q < d; q += 64) {
        float e = __expf(lrelu(s_i + dsth[nb[q]] + ab) - m);
        ev[h][q] = e;
        lp += e;
    }
    float l = wredsum(lp);
    __syncthreads();

    float acc = 0.f;
    const float* __restrict__ Whh = Wh + (size_t)h * N_NODES * NHID;
    if (d == 0) {
        acc = cm[h * NHID + lane];
    } else {
        #pragma unroll 4
        for (int q = 0; q < d; ++q) {
            float e = ev[h][q];
            int j = nb[q];
            acc += e * Whh[(size_t)j * NHID + lane];
        }
        acc *= (1.f / l);
    }
    float o = acc > 0.f ? acc : __expf(acc) - 1.f;   // elu
    hb[(size_t)i * (NHEADS * NHID) + h * NHID + lane] = f2bf(o);
}

// ---------------------------------------------------------------------------
// vec2 + colmeano fused: grid 1024 (4 rows/block src/dst) + 40 (colmean)
// ---------------------------------------------------------------------------
__global__ __launch_bounds__(256) void vecmean2(const float* __restrict__ Who,
                                                const float* __restrict__ ao,
                                                float* __restrict__ srco,
                                                float* __restrict__ dsto,
                                                float* __restrict__ cm) {
    const int bid = blockIdx.x;
    if (bid < 1024) {
        int i = bid * 4 + (threadIdx.x >> 6);
        int lane = threadIdx.x & 63;
        float v = (lane < NCLASS) ? Who[(size_t)i * NCLASS + lane] : 0.f;
        float s = (lane < NCLASS) ? v * ao[lane] : 0.f;
        float d = (lane < NCLASS) ? v * ao[NCLASS + lane] : 0.f;
        s = wredsum(s); d = wredsum(d);
        if (lane == 0) { srco[i] = s; dsto[i] = d; }
    } else {
        int n = bid - 1024;
        float s = 0.f;
        for (int r = threadIdx.x; r < N_NODES; r += 256) s += Who[(size_t)r * NCLASS + n];
        __shared__ float red[256];
        red[threadIdx.x] = s;
        __syncthreads();
        for (int st = 128; st; st >>= 1) {
            if (threadIdx.x < st) red[threadIdx.x] += red[threadIdx.x + st];
            __syncthreads();
        }
        if (threadIdx.x == 0) cm[n] = red[0] * (1.f / N_NODES);
    }
}

// ---------------------------------------------------------------------------
// output attention + elu + log_softmax: 4 rows/block, wave=row
// ---------------------------------------------------------------------------
__global__ __launch_bounds__(256) void attn2(const float* __restrict__ Who,
                                             const float* __restrict__ srco,
                                             const float* __restrict__ dsto,
                                             const float* __restrict__ abo_p,
                                             const float* __restrict__ cm,
                                             const int* __restrict__ deg,
                                             const unsigned short* __restrict__ nbr,
                                             float* __restrict__ out) {
    const int wid = threadIdx.x >> 6;
    const int i = blockIdx.x * 4 + wid;
    const int lane = threadIdx.x & 63;
    __shared__ unsigned short nb[4][MAXD];
    __shared__ float ev[4][MAXD];
    const float ab = abo_p[0];
    const int d = deg[i];
    for (int q = lane; q < d; q += 64) nb[wid][q] = nbr[(size_t)i * MAXD + q];
    const float s_i = srco[i];

    float m = -1e30f;
    for (int q = lane; q < d; q += 64) m = fmaxf(m, lrelu(s_i + dsto[nb[wid][q]] + ab));
    m = wredmax(m);

    float lp = 0.f;
    for (int q = lane; q < d; q += 64) {
        float e = __expf(lrelu(s_i + dsto[nb[wid][q]] + ab) - m);
        ev[wid][q] = e;
        lp += e;
    }
    float l = wredsum(lp);
    __syncthreads();

    float acc = 0.f;
    if (d == 0) {
        acc = (lane < NCLASS) ? cm[lane] : 0.f;
    } else {
        #pragma unroll 4
        for (int q = 0; q < d; ++q) {
            float e = ev[wid][q];
            int j = nb[wid][q];
            if (lane < NCLASS) acc += e * Who[(size_t)j * NCLASS + lane];
        }
        acc *= (1.f / l);
    }
    float v = acc > 0.f ? acc : __expf(acc) - 1.f;   // elu

    float xv = (lane < NCLASS) ? v : -1e30f;
    float mx = wredmax(xv);
    float ex = (lane < NCLASS) ? __expf(v - mx) : 0.f;
    ex = wredsum(ex);
    if (lane < NCLASS) out[(size_t)i * NCLASS + lane] = v - mx - logf(ex);
}

// ---------------------------------------------------------------------------
extern "C" void kernel_launch(void* const* d_in, const int* in_sizes, int n_in,
                              void* d_out, int out_size, void* d_ws, size_t ws_size,
                              hipStream_t stream) {
    const float* x   = (const float*)d_in[0];
    const int*   ei  = (const int*)d_in[1];
    const float* W1  = (const float*)d_in[2];
    const float* b1  = (const float*)d_in[3];
    const float* a1  = (const float*)d_in[4];
    const float* ab1 = (const float*)d_in[5];
    const float* Wo  = (const float*)d_in[6];
    const float* bo  = (const float*)d_in[7];
    const float* ao  = (const float*)d_in[8];
    const float* abo = (const float*)d_in[9];
    float* out = (float*)d_out;
    const int E = in_sizes[1] / 2;

    char* base = (char*)d_ws;
    const size_t MB = 1024 * 1024;
    // region 0: adj (2MB) -> reused as hb (bf16 4096x256 = 2MB) after compact
    unsigned long long* adj = (unsigned long long*)(base);
    unsigned short*     hb  = (unsigned short*)(base);
    // region 1: xb (bf16 4096x512 = 4MB) -> reused for Who/srco/dsto/cmo after gemm1
    unsigned short* xb   = (unsigned short*)(base + 2 * MB);
    float*          Who  = (float*)(base + 2 * MB);                 // 640KB
    float*          srco = (float*)(base + 3 * MB);                 // 16KB
    float*          dsto = (float*)(base + 3 * MB + 16384);         // 16KB
    float*          cmo  = (float*)(base + 3 * MB + 32768);         // small
    // region 2: Wh1 f32 [4][4096][64] = 4MB
    float* Wh1 = (float*)(base + 6 * MB);
    // region 3: persistent small buffers
    unsigned short* Bt   = (unsigned short*)(base + 10 * MB);            // 256KB
    unsigned short* Wot  = (unsigned short*)(base + 10 * MB + 262144);   // 32KB
    float*          src1 = (float*)(base + 10 * MB + 262144 + 32768);    // 64KB
    float*          dst1 = (float*)(base + 10 * MB + 262144 + 32768 + 65536);
    float*          cm1  = (float*)(base + 10 * MB + 262144 + 32768 + 131072);  // 1KB
    int*            deg  = (int*)(base + 10 * MB + 262144 + 32768 + 131072 + 4096); // 16KB
    unsigned short* nbr  = (unsigned short*)(base + 10 * MB + 262144 + 32768 + 131072 + 4096 + 16384); // 768KB

    castall<<<1472, 256, 0, stream>>>(x, W1, Wo, xb, Bt, Wot, (uint4*)adj);
    build_adj<<<(E + 255) / 256, 256, 0, stream>>>(ei, E, adj);
    compact<<<N_NODES / 4, 256, 0, stream>>>(adj, deg, nbr);
    gemm_mfma<<<dim3(64, NHEADS), 256, 0, stream>>>(xb, Bt, b1, Wh1, NFEAT, NHID, NHID);
    vecmean1<<<N_NODES + NHEADS, 256, 0, stream>>>(Wh1, a1, src1, dst1, cm1);
    attn1<<<N_NODES, 256, 0, stream>>>(Wh1, src1, dst1, ab1, cm1, deg, nbr, hb);
    gemm_mfma<<<dim3(64, 1), 256, 0, stream>>>(hb, Wot, bo, Who, NHEADS * NHID, NCLASS, NCLASS);
    vecmean2<<<1024 + NCLASS, 256, 0, stream>>>(Who, ao, srco, dsto, cmo);
    attn2<<<N_NODES / 4, 256, 0, stream>>>(Who, srco, dsto, abo, cmo, deg, nbr, out);
}